// Round 6
// baseline (37256.461 us; speedup 1.0000x reference)
//
#include <hip/hip_runtime.h>
#include <hip/hip_bf16.h>

#define Bz 32
#define Tz 1024
#define Iz 64
#define Hz 512
#define Az 16

// d_out layout (FP32 elems): out [B,T,A] | hn [1,B,H] | rnn_out [B,T,H]
#define OFF_HN  (Bz*Tz*Az)
#define OFF_RNN (OFF_HN + Bz*Hz)

typedef unsigned short u16;
typedef unsigned int u32;
typedef __attribute__((ext_vector_type(4))) float f32x4;

// ws layout (bytes)
#define WS_FLAGS 0x00000u   // int[1025*32] = 131200 B (zeroed each launch)
#define WS_RING  0x21000u   // float[4][32][512] = 262144 B; end 0x61000
#define WS_ZERO  0x21000u

__device__ __forceinline__ float sigmoidf_(float z) {
  return 1.0f / (1.0f + __expf(-z));
}

// ---------------------------------------------------------------------------
// Scan, pure VALU fp32. 32 blocks x 512 threads; block b owns cols [16b,16b+16).
// Thread (rr=tid>>4, nl=tid&15) computes h[rr][16b+nl]. h via 4-slot fp32 ring
// (agent-scope relaxed atomics); per-step per-block flags, release/acquire.
// ---------------------------------------------------------------------------
__global__ __launch_bounds__(512, 1) void rnn_scan_kernel(
    const float* __restrict__ inp,    // [B][T][I]
    const float* __restrict__ hn,     // [B][H]
    const float* __restrict__ whh,    // [k=H][n=H]
    const float* __restrict__ wih,    // [i=I][n=H]
    float* __restrict__ out_rnn,      // [B][T][H] fp32
    float* __restrict__ out_hn,       // [B][H] fp32
    int* __restrict__ flags,          // [1025][32] (zeroed)
    float* __restrict__ ring)         // [4][B][H] fp32
{
  const int tid  = threadIdx.x;
  const int lane = tid & 63;
  const int nl   = tid & 15;
  const int rr   = tid >> 4;         // 0..31
  const int c0   = blockIdx.x * 16;
  const int col  = c0 + nl;

  __hip_atomic_store(&ring[rr * Hz + col], hn[rr * Hz + col],
                     __ATOMIC_RELAXED, __HIP_MEMORY_SCOPE_AGENT);
  __threadfence();
  __syncthreads();
  if (tid == 0)
    __hip_atomic_store(&flags[blockIdx.x], 1, __ATOMIC_RELEASE,
                       __HIP_MEMORY_SCOPE_AGENT);

  for (int t = 0; t < Tz; ++t) {
    // x-projection (independent of h)
    float zx = 0.f;
    const float* ip = inp + ((size_t)rr * Tz + t) * Iz;
#pragma unroll
    for (int i = 0; i < Iz; i += 4) {
      zx += ip[i + 0] * wih[(i + 0) * Hz + col];
      zx += ip[i + 1] * wih[(i + 1) * Hz + col];
      zx += ip[i + 2] * wih[(i + 2) * Hz + col];
      zx += ip[i + 3] * wih[(i + 3) * Hz + col];
    }

    // Wait for h[t] from all 32 blocks (wave 0 polls in parallel)
    if (tid < 64) {
      int got;
      do {
        got = (lane < 32)
                  ? __hip_atomic_load(&flags[t * 32 + lane], __ATOMIC_ACQUIRE,
                                      __HIP_MEMORY_SCOPE_AGENT)
                  : 1;
      } while (!__all(got));
    }
    __syncthreads();

    // Recurrent part: z += sum_k h[rr][k] * whh[k][col]
    const float* hb = ring + (size_t)(t & 3) * (Bz * Hz) + (size_t)rr * Hz;
    float a0 = 0.f, a1 = 0.f, a2 = 0.f, a3 = 0.f;
    for (int k = 0; k < Hz; k += 4) {
      float h0v = __hip_atomic_load(hb + k + 0, __ATOMIC_RELAXED,
                                    __HIP_MEMORY_SCOPE_AGENT);
      float h1v = __hip_atomic_load(hb + k + 1, __ATOMIC_RELAXED,
                                    __HIP_MEMORY_SCOPE_AGENT);
      float h2v = __hip_atomic_load(hb + k + 2, __ATOMIC_RELAXED,
                                    __HIP_MEMORY_SCOPE_AGENT);
      float h3v = __hip_atomic_load(hb + k + 3, __ATOMIC_RELAXED,
                                    __HIP_MEMORY_SCOPE_AGENT);
      a0 += h0v * whh[(k + 0) * Hz + col];
      a1 += h1v * whh[(k + 1) * Hz + col];
      a2 += h2v * whh[(k + 2) * Hz + col];
      a3 += h3v * whh[(k + 3) * Hz + col];
    }
    float hnew = sigmoidf_(zx + ((a0 + a1) + (a2 + a3)));

    float* rn = ring + (size_t)((t + 1) & 3) * (Bz * Hz);
    __hip_atomic_store(&rn[rr * Hz + col], hnew, __ATOMIC_RELAXED,
                       __HIP_MEMORY_SCOPE_AGENT);
    out_rnn[((size_t)rr * Tz + t) * Hz + col] = hnew;
    if (t == Tz - 1) out_hn[rr * Hz + col] = hnew;

    __threadfence();
    __syncthreads();
    if (tid == 0)
      __hip_atomic_store(&flags[(t + 1) * 32 + blockIdx.x], 1, __ATOMIC_RELEASE,
                         __HIP_MEMORY_SCOPE_AGENT);
  }
}

// ---------------------------------------------------------------------------
// FC head, pure VALU fp32. 1024 blocks x 256 thr; block owns 32 X-rows.
// X (fp32 rnn_out region of d_out) staged into LDS; thread computes 2 hidden
// cols x 32 rows; hidden back to LDS; fused fc2 + sigmoid; fp32 stores.
// ---------------------------------------------------------------------------
__global__ __launch_bounds__(256) void fc_kernel(
    const float* __restrict__ X,  // [32768][512] fp32 (= rnn_out)
    const float* __restrict__ w1, // [k=512][n=512]
    const float* __restrict__ b1, // [512]
    const float* __restrict__ w2, // [n=512][a=16]
    const float* __restrict__ b2, // [16]
    float* __restrict__ out)      // [32768][16] fp32
{
  __shared__ float XL[Bz * Hz];   // 64 KB
  const int tid = threadIdx.x;
  const size_t r0 = (size_t)blockIdx.x * 32;

  for (int ch = tid; ch < (Bz * Hz) / 4; ch += 256) {
    int e = ch * 4;
    int row = e >> 9, k = e & 511;
    *(f32x4*)(&XL[row * Hz + k]) = *(const f32x4*)(X + (r0 + row) * Hz + k);
  }
  __syncthreads();

  const int c0 = tid;
  const int c1 = tid + 256;
  float acc0[32], acc1[32];
  {
    float bb0 = b1[c0], bb1 = b1[c1];
#pragma unroll
    for (int m = 0; m < 32; ++m) { acc0[m] = bb0; acc1[m] = bb1; }
  }
  for (int kk = 0; kk < Hz; kk += 4) {
    float w00 = w1[(kk + 0) * Hz + c0];
    float w01 = w1[(kk + 1) * Hz + c0];
    float w02 = w1[(kk + 2) * Hz + c0];
    float w03 = w1[(kk + 3) * Hz + c0];
    float w10 = w1[(kk + 0) * Hz + c1];
    float w11 = w1[(kk + 1) * Hz + c1];
    float w12 = w1[(kk + 2) * Hz + c1];
    float w13 = w1[(kk + 3) * Hz + c1];
#pragma unroll
    for (int m = 0; m < 32; ++m) {
      f32x4 x = *(const f32x4*)(&XL[m * Hz + kk]);
      acc0[m] += x.x * w00 + x.y * w01 + x.z * w02 + x.w * w03;
      acc1[m] += x.x * w10 + x.y * w11 + x.z * w12 + x.w * w13;
    }
  }
  __syncthreads();
#pragma unroll
  for (int m = 0; m < 32; ++m) {
    XL[m * Hz + c0] = fmaxf(acc0[m], 0.f);
    XL[m * Hz + c1] = fmaxf(acc1[m], 0.f);
  }
  __syncthreads();

  for (int oi = tid; oi < Bz * Az; oi += 256) {
    int m = oi >> 4, a = oi & 15;
    float acc = b2[a];
    for (int nn = 0; nn < Hz; nn += 4) {
      f32x4 hv = *(const f32x4*)(&XL[m * Hz + nn]);
      acc += hv.x * w2[(nn + 0) * Az + a];
      acc += hv.y * w2[(nn + 1) * Az + a];
      acc += hv.z * w2[(nn + 2) * Az + a];
      acc += hv.w * w2[(nn + 3) * Az + a];
    }
    out[(r0 + m) * Az + a] = sigmoidf_(acc);
  }
}

extern "C" void kernel_launch(void* const* d_in, const int* in_sizes, int n_in,
                              void* d_out, int out_size, void* d_ws, size_t ws_size,
                              hipStream_t stream) {
  // Permutation detection from in_sizes (insurance; sizes unique except the
  // two 512x512 weights, disambiguated by b1-vs-inp relative position).
  int idx_inp = 0, idx_hn = 1, idx_wih = 3, idx_b1 = 5, idx_w2 = 6, idx_b2 = 7;
  int amb1 = -1, amb2 = -1, found = 0;
  for (int i = 0; i < 8 && i < n_in; ++i) {
    switch (in_sizes[i]) {
      case 2097152: idx_inp = i; found |= 1; break;
      case 16384:   idx_hn  = i; found |= 2; break;
      case 32768:   idx_wih = i; found |= 4; break;
      case 512:     idx_b1  = i; found |= 8; break;
      case 8192:    idx_w2  = i; found |= 16; break;
      case 16:      idx_b2  = i; found |= 32; break;
      case 262144:  if (amb1 < 0) amb1 = i; else amb2 = i; break;
    }
  }
  int idx_whh = 2, idx_w1 = 4;  // dict-order fallback
  if (amb1 >= 0 && amb2 >= 0 && found == 63) {
    if (idx_b1 < idx_inp) { idx_w1 = amb1; idx_whh = amb2; }
    else                  { idx_whh = amb1; idx_w1 = amb2; }
  }

  const float* inp = (const float*)d_in[idx_inp];
  const float* hn  = (const float*)d_in[idx_hn];
  const float* whh = (const float*)d_in[idx_whh];
  const float* wih = (const float*)d_in[idx_wih];
  const float* w1  = (const float*)d_in[idx_w1];
  const float* b1  = (const float*)d_in[idx_b1];
  const float* w2  = (const float*)d_in[idx_w2];
  const float* b2  = (const float*)d_in[idx_b2];

  float* out     = (float*)d_out;
  float* out_hn  = out + OFF_HN;
  float* out_rnn = out + OFF_RNN;

  char* ws    = (char*)d_ws;
  int* flags  = (int*)(ws + WS_FLAGS);
  float* ring = (float*)(ws + WS_RING);

  hipMemsetAsync(d_ws, 0, WS_ZERO, stream);
  rnn_scan_kernel<<<dim3(32), dim3(512), 0, stream>>>(
      inp, hn, whh, wih, out_rnn, out_hn, flags, ring);
  fc_kernel<<<dim3(Bz * Tz / 32), dim3(256), 0, stream>>>(
      out_rnn, w1, b1, w2, b2, out);
}

// Round 7
// 8207.246 us; speedup vs baseline: 4.5395x; 4.5395x over previous
//
#include <hip/hip_runtime.h>
#include <hip/hip_bf16.h>

#define Bz 32
#define Tz 1024
#define Iz 64
#define Hz 512
#define Az 16

// d_out layout (FP32 elems): out [B,T,A] | hn [1,B,H] | rnn_out [B,T,H]
#define OFF_HN  (Bz*Tz*Az)
#define OFF_RNN (OFF_HN + Bz*Hz)

typedef unsigned short u16;
typedef unsigned int u32;
typedef __attribute__((ext_vector_type(8))) unsigned short u16x8;
typedef __attribute__((ext_vector_type(4))) unsigned int u32x4;
typedef __attribute__((ext_vector_type(8))) __bf16 bf16x8;
typedef __attribute__((ext_vector_type(4))) float f32x4;

// ws layout (bytes)
#define WS_FLAGS 0x00000u   // int[1025*32] = 131200 B (zeroed each launch)
#define WS_RING  0x21000u   // u16[4][32][512] = 131072 B
#define WS_WHH   0x41000u   // u16[512*512] bf16 = 512 KB
#define WS_WIH   0xC1000u   // u16[64*512] bf16 = 64 KB; end 0xD1000
#define WS_ZERO  0x21000u

__device__ __forceinline__ u16 f2bf(float f) {
  union { float f; unsigned int i; } x; x.f = f;
  unsigned int r = (x.i + 0x7FFFu + ((x.i >> 16) & 1u)) >> 16;
  return (u16)r;
}
__device__ __forceinline__ float sigmoidf_(float z) {
  return 1.0f / (1.0f + __expf(-z));
}

// ---------------------------------------------------------------------------
// Prep: fp32 -> bf16 copies of w_hh, w_ih (layout preserved: [k][n])
// ---------------------------------------------------------------------------
__global__ void prep_kernel(const float* __restrict__ whh,
                            const float* __restrict__ wih,
                            u16* __restrict__ whh_bf,
                            u16* __restrict__ wih_bf) {
  int idx = blockIdx.x * 256 + threadIdx.x;
  if (idx < 262144) {
    whh_bf[idx] = f2bf(whh[idx]);
  } else if (idx < 294912) {
    int i = idx - 262144;
    wih_bf[i] = f2bf(wih[i]);
  }
}

// ---------------------------------------------------------------------------
// Scan (R2 structure, HW-proven correct): 32 blocks x 128 thr (2 waves).
// Block b owns cols [16b,16b+16); wave w owns batch rows [16w,16w+16).
// W_hh (64 VGPR) + W_ih (8 VGPR) fragments register-resident for all T steps.
// h exchanged bf16 via 4-slot ring in ws using agent-scope relaxed u32
// atomics (stores packed via shfl, loads as A-fragment dword gathers).
// Flags: per-block slot per step; release store / 32-lane acquire poll.
// MFMA 16x16x32 bf16: A m=lane&15,k=q*8+j; B n=lane&15,k=q*8+j;
//                     C/D col=lane&15,row=q*4+reg.
// ---------------------------------------------------------------------------
__global__ __launch_bounds__(128, 1) void rnn_scan_kernel(
    const float* __restrict__ inp,   // [B][T][I] fp32
    const float* __restrict__ hn,    // [B][H] fp32
    const u16* __restrict__ whh_bf,  // [k=H][n=H] bf16
    const u16* __restrict__ wih_bf,  // [i=I][n=H] bf16
    float* __restrict__ out_rnn,     // [B][T][H] fp32
    float* __restrict__ out_hn,      // [B][H] fp32
    int* __restrict__ flags,         // [1025][32] (zeroed)
    u16* __restrict__ hbuf)          // [4][B][H] bf16 ring
{
  const int tid  = threadIdx.x;
  const int lane = tid & 63;
  const int wave = tid >> 6;
  const int ln   = lane & 15;
  const int q    = lane >> 4;
  const int c0   = blockIdx.x * 16;
  const int col  = c0 + ln;
  const int arow = wave * 16 + ln;

  // Preload B fragments (one-time gathers from bf16 copies)
  bf16x8 bhh[16];
#pragma unroll
  for (int kt = 0; kt < 16; ++kt) {
    u16x8 f;
#pragma unroll
    for (int j = 0; j < 8; ++j) f[j] = whh_bf[(kt * 32 + q * 8 + j) * Hz + col];
    bhh[kt] = __builtin_bit_cast(bf16x8, f);
  }
  bf16x8 bih[2];
#pragma unroll
  for (int kt = 0; kt < 2; ++kt) {
    u16x8 f;
#pragma unroll
    for (int j = 0; j < 8; ++j) f[j] = wih_bf[(kt * 32 + q * 8 + j) * Hz + col];
    bih[kt] = __builtin_bit_cast(bf16x8, f);
  }

  // Init ring slot 0 (all 32 rows, own 16 cols) — packed coherent u32 stores
  for (int i = tid; i < Bz * 8; i += 128) {
    int r = i >> 3, cc = c0 + (i & 7) * 2;
    u32 pk = (u32)f2bf(hn[r * Hz + cc]) | ((u32)f2bf(hn[r * Hz + cc + 1]) << 16);
    __hip_atomic_store((u32*)(hbuf + r * Hz + cc), pk, __ATOMIC_RELAXED,
                       __HIP_MEMORY_SCOPE_AGENT);
  }
  __threadfence();
  __syncthreads();
  if (tid == 0)
    __hip_atomic_store(&flags[blockIdx.x], 1, __ATOMIC_RELEASE,
                       __HIP_MEMORY_SCOPE_AGENT);

  for (int t = 0; t < Tz; ++t) {
    // Issue inp loads early (read-only input, plain loads fine)
    const float* ipb = inp + ((size_t)arow * Tz + t) * Iz + q * 8;
    f32x4 x0 = *(const f32x4*)(ipb);
    f32x4 x1 = *(const f32x4*)(ipb + 4);
    f32x4 x2 = *(const f32x4*)(ipb + 32);
    f32x4 x3 = *(const f32x4*)(ipb + 36);

    // Wait for h[t]: wave 0 polls 32 per-block flags in parallel
    if (tid < 64) {
      int got;
      do {
        got = (lane < 32)
                  ? __hip_atomic_load(&flags[t * 32 + lane], __ATOMIC_ACQUIRE,
                                      __HIP_MEMORY_SCOPE_AGENT)
                  : 1;
      } while (!__all(got));
    }
    __syncthreads();

    // Pack inp to bf16 A-fragments
    u16x8 ax0, ax1;
#pragma unroll
    for (int j = 0; j < 4; ++j) {
      ax0[j]     = f2bf(x0[j]);
      ax0[4 + j] = f2bf(x1[j]);
      ax1[j]     = f2bf(x2[j]);
      ax1[4 + j] = f2bf(x3[j]);
    }

    // Coherent A-fragment loads from h ring (u32 atomics, agent scope)
    const u32* hb32 = (const u32*)hbuf + (t & 3) * (Bz * Hz / 2) + arow * (Hz / 2);
    f32x4 acc0 = {0.f, 0.f, 0.f, 0.f};
    f32x4 acc1 = {0.f, 0.f, 0.f, 0.f};
    acc0 = __builtin_amdgcn_mfma_f32_16x16x32_bf16(
        __builtin_bit_cast(bf16x8, ax0), bih[0], acc0, 0, 0, 0);
    acc1 = __builtin_amdgcn_mfma_f32_16x16x32_bf16(
        __builtin_bit_cast(bf16x8, ax1), bih[1], acc1, 0, 0, 0);
#pragma unroll
    for (int kt = 0; kt < 16; kt += 2) {
      u32x4 v0, v1;
      const u32* p0 = hb32 + kt * 16 + q * 4;
      const u32* p1 = hb32 + (kt + 1) * 16 + q * 4;
      v0.x = __hip_atomic_load(p0 + 0, __ATOMIC_RELAXED, __HIP_MEMORY_SCOPE_AGENT);
      v0.y = __hip_atomic_load(p0 + 1, __ATOMIC_RELAXED, __HIP_MEMORY_SCOPE_AGENT);
      v0.z = __hip_atomic_load(p0 + 2, __ATOMIC_RELAXED, __HIP_MEMORY_SCOPE_AGENT);
      v0.w = __hip_atomic_load(p0 + 3, __ATOMIC_RELAXED, __HIP_MEMORY_SCOPE_AGENT);
      v1.x = __hip_atomic_load(p1 + 0, __ATOMIC_RELAXED, __HIP_MEMORY_SCOPE_AGENT);
      v1.y = __hip_atomic_load(p1 + 1, __ATOMIC_RELAXED, __HIP_MEMORY_SCOPE_AGENT);
      v1.z = __hip_atomic_load(p1 + 2, __ATOMIC_RELAXED, __HIP_MEMORY_SCOPE_AGENT);
      v1.w = __hip_atomic_load(p1 + 3, __ATOMIC_RELAXED, __HIP_MEMORY_SCOPE_AGENT);
      acc0 = __builtin_amdgcn_mfma_f32_16x16x32_bf16(
          __builtin_bit_cast(bf16x8, v0), bhh[kt], acc0, 0, 0, 0);
      acc1 = __builtin_amdgcn_mfma_f32_16x16x32_bf16(
          __builtin_bit_cast(bf16x8, v1), bhh[kt + 1], acc1, 0, 0, 0);
    }
    f32x4 acc = acc0 + acc1;

    // Epilogue: sigmoid; packed coherent u32 ring stores; fp32 output stores
    u16* hbn = hbuf + ((t + 1) & 3) * (Bz * Hz);
#pragma unroll
    for (int r = 0; r < 4; ++r) {
      int brow = wave * 16 + q * 4 + r;
      float hf = sigmoidf_(acc[r]);
      u16 h16 = f2bf(hf);
      u32 mine = h16;
      u32 other = (u32)__shfl_xor((int)mine, 1, 64);
      if (!(ln & 1)) {
        u32 pk = mine | (other << 16);
        __hip_atomic_store((u32*)(hbn + brow * Hz + col), pk, __ATOMIC_RELAXED,
                           __HIP_MEMORY_SCOPE_AGENT);
      }
      out_rnn[((size_t)brow * Tz + t) * Hz + col] = hf;
      if (t == Tz - 1) out_hn[brow * Hz + col] = hf;
    }
    __threadfence();
    __syncthreads();  // all stores issued before flag release
    if (tid == 0)
      __hip_atomic_store(&flags[(t + 1) * 32 + blockIdx.x], 1, __ATOMIC_RELEASE,
                         __HIP_MEMORY_SCOPE_AGENT);
  }
}

// ---------------------------------------------------------------------------
// FC head, pure VALU fp32 (unchanged from R6 — proven). 1024 blocks x 256 thr.
// ---------------------------------------------------------------------------
__global__ __launch_bounds__(256) void fc_kernel(
    const float* __restrict__ X,  // [32768][512] fp32 (= rnn_out)
    const float* __restrict__ w1, // [k=512][n=512]
    const float* __restrict__ b1, // [512]
    const float* __restrict__ w2, // [n=512][a=16]
    const float* __restrict__ b2, // [16]
    float* __restrict__ out)      // [32768][16] fp32
{
  __shared__ float XL[Bz * Hz];   // 64 KB
  const int tid = threadIdx.x;
  const size_t r0 = (size_t)blockIdx.x * 32;

  for (int ch = tid; ch < (Bz * Hz) / 4; ch += 256) {
    int e = ch * 4;
    int row = e >> 9, k = e & 511;
    *(f32x4*)(&XL[row * Hz + k]) = *(const f32x4*)(X + (r0 + row) * Hz + k);
  }
  __syncthreads();

  const int c0 = tid;
  const int c1 = tid + 256;
  float acc0[32], acc1[32];
  {
    float bb0 = b1[c0], bb1 = b1[c1];
#pragma unroll
    for (int m = 0; m < 32; ++m) { acc0[m] = bb0; acc1[m] = bb1; }
  }
  for (int kk = 0; kk < Hz; kk += 4) {
    float w00 = w1[(kk + 0) * Hz + c0];
    float w01 = w1[(kk + 1) * Hz + c0];
    float w02 = w1[(kk + 2) * Hz + c0];
    float w03 = w1[(kk + 3) * Hz + c0];
    float w10 = w1[(kk + 0) * Hz + c1];
    float w11 = w1[(kk + 1) * Hz + c1];
    float w12 = w1[(kk + 2) * Hz + c1];
    float w13 = w1[(kk + 3) * Hz + c1];
#pragma unroll
    for (int m = 0; m < 32; ++m) {
      f32x4 x = *(const f32x4*)(&XL[m * Hz + kk]);
      acc0[m] += x.x * w00 + x.y * w01 + x.z * w02 + x.w * w03;
      acc1[m] += x.x * w10 + x.y * w11 + x.z * w12 + x.w * w13;
    }
  }
  __syncthreads();
#pragma unroll
  for (int m = 0; m < 32; ++m) {
    XL[m * Hz + c0] = fmaxf(acc0[m], 0.f);
    XL[m * Hz + c1] = fmaxf(acc1[m], 0.f);
  }
  __syncthreads();

  for (int oi = tid; oi < Bz * Az; oi += 256) {
    int m = oi >> 4, a = oi & 15;
    float acc = b2[a];
    for (int nn = 0; nn < Hz; nn += 4) {
      f32x4 hv = *(const f32x4*)(&XL[m * Hz + nn]);
      acc += hv.x * w2[(nn + 0) * Az + a];
      acc += hv.y * w2[(nn + 1) * Az + a];
      acc += hv.z * w2[(nn + 2) * Az + a];
      acc += hv.w * w2[(nn + 3) * Az + a];
    }
    out[(r0 + m) * Az + a] = sigmoidf_(acc);
  }
}

extern "C" void kernel_launch(void* const* d_in, const int* in_sizes, int n_in,
                              void* d_out, int out_size, void* d_ws, size_t ws_size,
                              hipStream_t stream) {
  // Permutation detection from in_sizes (insurance; proven harmless in R6)
  int idx_inp = 0, idx_hn = 1, idx_wih = 3, idx_b1 = 5, idx_w2 = 6, idx_b2 = 7;
  int amb1 = -1, amb2 = -1, found = 0;
  for (int i = 0; i < 8 && i < n_in; ++i) {
    switch (in_sizes[i]) {
      case 2097152: idx_inp = i; found |= 1; break;
      case 16384:   idx_hn  = i; found |= 2; break;
      case 32768:   idx_wih = i; found |= 4; break;
      case 512:     idx_b1  = i; found |= 8; break;
      case 8192:    idx_w2  = i; found |= 16; break;
      case 16:      idx_b2  = i; found |= 32; break;
      case 262144:  if (amb1 < 0) amb1 = i; else amb2 = i; break;
    }
  }
  int idx_whh = 2, idx_w1 = 4;  // dict-order fallback
  if (amb1 >= 0 && amb2 >= 0 && found == 63) {
    if (idx_b1 < idx_inp) { idx_w1 = amb1; idx_whh = amb2; }
    else                  { idx_whh = amb1; idx_w1 = amb2; }
  }

  const float* inp = (const float*)d_in[idx_inp];
  const float* hn  = (const float*)d_in[idx_hn];
  const float* whh = (const float*)d_in[idx_whh];
  const float* wih = (const float*)d_in[idx_wih];
  const float* w1  = (const float*)d_in[idx_w1];
  const float* b1  = (const float*)d_in[idx_b1];
  const float* w2  = (const float*)d_in[idx_w2];
  const float* b2  = (const float*)d_in[idx_b2];

  float* out     = (float*)d_out;
  float* out_hn  = out + OFF_HN;
  float* out_rnn = out + OFF_RNN;

  char* ws    = (char*)d_ws;
  int* flags  = (int*)(ws + WS_FLAGS);
  u16* hbuf   = (u16*)(ws + WS_RING);
  u16* whh_bf = (u16*)(ws + WS_WHH);
  u16* wih_bf = (u16*)(ws + WS_WIH);

  hipMemsetAsync(d_ws, 0, WS_ZERO, stream);
  prep_kernel<<<dim3(1152), dim3(256), 0, stream>>>(whh, wih, whh_bf, wih_bf);
  rnn_scan_kernel<<<dim3(32), dim3(128), 0, stream>>>(
      inp, hn, whh_bf, wih_bf, out_rnn, out_hn, flags, hbuf);
  fc_kernel<<<dim3(Bz * Tz / 32), dim3(256), 0, stream>>>(
      out_rnn, w1, b1, w2, b2, out);
}

// Round 8
// 5062.931 us; speedup vs baseline: 7.3587x; 1.6210x over previous
//
#include <hip/hip_runtime.h>
#include <hip/hip_bf16.h>

#define Bz 32
#define Tz 1024
#define Iz 64
#define Hz 512
#define Az 16

// d_out layout (FP32 elems): out [B,T,A] | hn [1,B,H] | rnn_out [B,T,H]
#define OFF_HN  (Bz*Tz*Az)
#define OFF_RNN (OFF_HN + Bz*Hz)

typedef unsigned short u16;
typedef unsigned int u32;
typedef unsigned long long u64;
typedef __attribute__((ext_vector_type(8))) unsigned short u16x8;
typedef __attribute__((ext_vector_type(8))) __bf16 bf16x8;
typedef __attribute__((ext_vector_type(4))) float f32x4;

// ws layout (bytes)
#define WS_FLAGS 0x00000u   // int[1025*32] = 131200 B (zeroed each launch)
#define WS_RING  0x21000u   // u16[4][32][512] = 131072 B
#define WS_WHH   0x41000u   // u16[512*512] bf16 = 512 KB
#define WS_WIH   0xC1000u   // u16[64*512] bf16 = 64 KB
#define WS_W1T   0xD1000u   // u16[512*512] bf16 [n][k]; end 0x151000 (~1.35 MB)
#define WS_ZERO  0x21000u

__device__ __forceinline__ u16 f2bf(float f) {
  union { float f; unsigned int i; } x; x.f = f;
  unsigned int r = (x.i + 0x7FFFu + ((x.i >> 16) & 1u)) >> 16;
  return (u16)r;
}
__device__ __forceinline__ float bf2f(u16 u) {
  union { unsigned int i; float f; } x; x.i = ((unsigned int)u) << 16; return x.f;
}
__device__ __forceinline__ float sigmoidf_(float z) {
  return 1.0f / (1.0f + __expf(-z));
}

// ---------------------------------------------------------------------------
// Prep: fp32 -> bf16 copies (w_hh, w_ih layout-preserved; fc1_w transposed)
// ---------------------------------------------------------------------------
__global__ void prep_kernel(const float* __restrict__ whh,
                            const float* __restrict__ wih,
                            const float* __restrict__ w1,
                            u16* __restrict__ whh_bf,
                            u16* __restrict__ wih_bf,
                            u16* __restrict__ w1t_bf) {
  int idx = blockIdx.x * 256 + threadIdx.x;
  if (idx < 262144) {
    whh_bf[idx] = f2bf(whh[idx]);
  } else if (idx < 294912) {
    int i = idx - 262144;
    wih_bf[i] = f2bf(wih[i]);
  } else if (idx < 557056) {
    int j = idx - 294912;
    int n = j >> 9, k = j & 511;
    w1t_bf[n * Hz + k] = f2bf(w1[k * Hz + n]);  // [n][k] <- [k][n]
  }
}

// ---------------------------------------------------------------------------
// Scan: 32 blocks x 128 thr (2 waves). Block b owns cols [16b,16b+16).
// All-RELAXED coherent protocol (no fences/wbl2 on the critical path):
//   producer: ring atomic-stores -> __syncthreads (drains own vmcnt; stores
//   are at the coherence point) -> relaxed flag store -> plain output stores.
//   consumer: relaxed flag poll (loop exits only after the flag load RETURNS
//   1, so subsequent coherent loads access L3 strictly later) -> syncthreads
//   (compiler barrier) -> 32 u64 atomic loads issued up-front (one pipelined
//   L3 round trip) -> 18 MFMA.
// MFMA 16x16x32 bf16 (HW-proven R7): A m=lane&15,k=q*8+j; B n=lane&15,k=q*8+j;
//                                    C/D col=lane&15,row=q*4+reg.
// ---------------------------------------------------------------------------
__global__ __launch_bounds__(128, 1) void rnn_scan_kernel(
    const float* __restrict__ inp,   // [B][T][I] fp32
    const float* __restrict__ hn,    // [B][H] fp32
    const u16* __restrict__ whh_bf,  // [k=H][n=H] bf16
    const u16* __restrict__ wih_bf,  // [i=I][n=H] bf16
    float* __restrict__ out_rnn,     // [B][T][H] fp32
    float* __restrict__ out_hn,      // [B][H] fp32
    int* __restrict__ flags,         // [1025][32] (zeroed)
    u16* __restrict__ hbuf)          // [4][B][H] bf16 ring
{
  const int tid  = threadIdx.x;
  const int lane = tid & 63;
  const int wave = tid >> 6;
  const int ln   = lane & 15;
  const int q    = lane >> 4;
  const int c0   = blockIdx.x * 16;
  const int col  = c0 + ln;
  const int arow = wave * 16 + ln;

  // Preload B fragments (one-time gathers from bf16 copies)
  bf16x8 bhh[16];
#pragma unroll
  for (int kt = 0; kt < 16; ++kt) {
    u16x8 f;
#pragma unroll
    for (int j = 0; j < 8; ++j) f[j] = whh_bf[(kt * 32 + q * 8 + j) * Hz + col];
    bhh[kt] = __builtin_bit_cast(bf16x8, f);
  }
  bf16x8 bih[2];
#pragma unroll
  for (int kt = 0; kt < 2; ++kt) {
    u16x8 f;
#pragma unroll
    for (int j = 0; j < 8; ++j) f[j] = wih_bf[(kt * 32 + q * 8 + j) * Hz + col];
    bih[kt] = __builtin_bit_cast(bf16x8, f);
  }

  // Init ring slot 0 (all 32 rows, own 16 cols) — packed coherent u32 stores
  for (int i = tid; i < Bz * 8; i += 128) {
    int r = i >> 3, cc = c0 + (i & 7) * 2;
    u32 pk = (u32)f2bf(hn[r * Hz + cc]) | ((u32)f2bf(hn[r * Hz + cc + 1]) << 16);
    __hip_atomic_store((u32*)(hbuf + r * Hz + cc), pk, __ATOMIC_RELAXED,
                       __HIP_MEMORY_SCOPE_AGENT);
  }
  __syncthreads();
  if (tid == 0)
    __hip_atomic_store(&flags[blockIdx.x], 1, __ATOMIC_RELAXED,
                       __HIP_MEMORY_SCOPE_AGENT);

  for (int t = 0; t < Tz; ++t) {
    // inp loads + bf16 pack — all before the poll (off critical path)
    const float* ipb = inp + ((size_t)arow * Tz + t) * Iz + q * 8;
    f32x4 x0 = *(const f32x4*)(ipb);
    f32x4 x1 = *(const f32x4*)(ipb + 4);
    f32x4 x2 = *(const f32x4*)(ipb + 32);
    f32x4 x3 = *(const f32x4*)(ipb + 36);
    u16x8 ax0, ax1;
#pragma unroll
    for (int j = 0; j < 4; ++j) {
      ax0[j]     = f2bf(x0[j]);
      ax0[4 + j] = f2bf(x1[j]);
      ax1[j]     = f2bf(x2[j]);
      ax1[4 + j] = f2bf(x3[j]);
    }

    // Relaxed poll: wave 0 watches all 32 per-block flags in parallel
    if (tid < 64) {
      int got;
      do {
        got = (lane < 32)
                  ? __hip_atomic_load(&flags[t * 32 + lane], __ATOMIC_RELAXED,
                                      __HIP_MEMORY_SCOPE_AGENT)
                  : 1;
      } while (!__all(got));
    }
    __syncthreads();

    // Issue ALL h-fragment loads up front (32 u64 coherent loads -> 1 L3 RT)
    const u64* hb64 = (const u64*)hbuf + (size_t)(t & 3) * (Bz * Hz / 4) +
                      (size_t)arow * (Hz / 4);
    u64 hreg[32];
#pragma unroll
    for (int kt = 0; kt < 16; ++kt) {
      hreg[2 * kt]     = __hip_atomic_load(hb64 + kt * 8 + q * 2,
                                           __ATOMIC_RELAXED,
                                           __HIP_MEMORY_SCOPE_AGENT);
      hreg[2 * kt + 1] = __hip_atomic_load(hb64 + kt * 8 + q * 2 + 1,
                                           __ATOMIC_RELAXED,
                                           __HIP_MEMORY_SCOPE_AGENT);
    }

    f32x4 acc0 = {0.f, 0.f, 0.f, 0.f};
    f32x4 acc1 = {0.f, 0.f, 0.f, 0.f};
    // Input-projection MFMAs first (independent of h loads — overlap latency)
    acc0 = __builtin_amdgcn_mfma_f32_16x16x32_bf16(
        __builtin_bit_cast(bf16x8, ax0), bih[0], acc0, 0, 0, 0);
    acc1 = __builtin_amdgcn_mfma_f32_16x16x32_bf16(
        __builtin_bit_cast(bf16x8, ax1), bih[1], acc1, 0, 0, 0);
#pragma unroll
    for (int kt = 0; kt < 16; kt += 2) {
      u64 v0[2] = {hreg[2 * kt], hreg[2 * kt + 1]};
      u64 v1[2] = {hreg[2 * kt + 2], hreg[2 * kt + 3]};
      acc0 = __builtin_amdgcn_mfma_f32_16x16x32_bf16(
          __builtin_bit_cast(bf16x8, v0), bhh[kt], acc0, 0, 0, 0);
      acc1 = __builtin_amdgcn_mfma_f32_16x16x32_bf16(
          __builtin_bit_cast(bf16x8, v1), bhh[kt + 1], acc1, 0, 0, 0);
    }
    f32x4 acc = acc0 + acc1;

    // Epilogue: sigmoid; packed coherent u32 ring stores
    u16* hbn = hbuf + ((t + 1) & 3) * (Bz * Hz);
    float hf[4];
#pragma unroll
    for (int r = 0; r < 4; ++r) {
      int brow = wave * 16 + q * 4 + r;
      hf[r] = sigmoidf_(acc[r]);
      u32 mine = (u32)f2bf(hf[r]);
      u32 other = (u32)__shfl_xor((int)mine, 1, 64);
      if (!(ln & 1)) {
        u32 pk = mine | (other << 16);
        __hip_atomic_store((u32*)(hbn + brow * Hz + col), pk, __ATOMIC_RELAXED,
                           __HIP_MEMORY_SCOPE_AGENT);
      }
    }
    __syncthreads();  // each thread's ring stores are complete (vmcnt drained)
    if (tid == 0)
      __hip_atomic_store(&flags[(t + 1) * 32 + blockIdx.x], 1, __ATOMIC_RELAXED,
                         __HIP_MEMORY_SCOPE_AGENT);
    // Output stores AFTER the flag release — off the critical path
#pragma unroll
    for (int r = 0; r < 4; ++r) {
      int brow = wave * 16 + q * 4 + r;
      out_rnn[((size_t)brow * Tz + t) * Hz + col] = hf[r];
      if (t == Tz - 1) out_hn[brow * Hz + col] = hf[r];
    }
  }
}

// ---------------------------------------------------------------------------
// FC head (R3-lineage, retro-validated by R2/R3<->R6 bit-identity):
// 256 blocks x 256 thr; block owns 128 rows x ALL 512 cols of fc1 (MFMA bf16,
// tile 128x128, BK=64); hidden tile through LDS; fc2 VALU-accumulated in
// registers; fp32 in (cvt on stage) / fp32 out.
// ---------------------------------------------------------------------------
__global__ __launch_bounds__(256, 2) void fc_kernel(
    const float* __restrict__ X,  // [32768][512] fp32 (= rnn_out)
    const u16* __restrict__ w1t,  // [n=512][k=512] bf16
    const float* __restrict__ b1, // [512] fp32
    const float* __restrict__ w2, // [n=512][a=16] fp32
    const float* __restrict__ b2, // [16] fp32
    float* __restrict__ out)      // [32768][16] fp32
{
  __shared__ u16 smem[18432];     // 36 KB
  u16* As = smem;                 // [128][72]
  u16* Bs = smem + 9216;          // [128][72]
  u16* Ht = smem;                 // [128][136] (reused, 34816 B)

  const int tid  = threadIdx.x;
  const int lane = tid & 63;
  const int wv   = tid >> 6;
  const int ln   = lane & 15, q = lane >> 4;
  const int mq   = (wv & 1) * 64, nq = (wv >> 1) * 64;
  const size_t r0 = (size_t)blockIdx.x * 128;
  const int om = tid >> 1;          // output row 0..127
  const int oa = (tid & 1) * 8;     // output col half

  float oacc[8];
#pragma unroll
  for (int j = 0; j < 8; ++j) oacc[j] = 0.f;

  for (int nt = 0; nt < 4; ++nt) {
    const int n0 = nt * 128;
    f32x4 acc[4][4];
#pragma unroll
    for (int mi = 0; mi < 4; ++mi)
#pragma unroll
      for (int ni = 0; ni < 4; ++ni) acc[mi][ni] = (f32x4){0.f, 0.f, 0.f, 0.f};

    for (int kb = 0; kb < 8; ++kb) {
      const int K0 = kb * 64;
      __syncthreads();  // prior frag/Ht reads done before restaging
      for (int i = tid; i < 1024; i += 256) {
        int row = i >> 3, c = (i & 7) * 8;
        f32x4 lo = *(const f32x4*)(X + (r0 + row) * Hz + K0 + c);
        f32x4 hi = *(const f32x4*)(X + (r0 + row) * Hz + K0 + c + 4);
        u16x8 p;
#pragma unroll
        for (int j = 0; j < 4; ++j) { p[j] = f2bf(lo[j]); p[4 + j] = f2bf(hi[j]); }
        *(u16x8*)(As + row * 72 + c) = p;
      }
      for (int i = tid; i < 1024; i += 256) {
        int row = i >> 3, c = (i & 7) * 8;
        *(u16x8*)(Bs + row * 72 + c) =
            *(const u16x8*)(w1t + (size_t)(n0 + row) * Hz + K0 + c);
      }
      __syncthreads();
#pragma unroll
      for (int kt = 0; kt < 2; ++kt) {
        bf16x8 af[4], bfr[4];
#pragma unroll
        for (int mi = 0; mi < 4; ++mi)
          af[mi] = __builtin_bit_cast(
              bf16x8,
              *(const u16x8*)(As + (mq + mi * 16 + ln) * 72 + kt * 32 + q * 8));
#pragma unroll
        for (int ni = 0; ni < 4; ++ni)
          bfr[ni] = __builtin_bit_cast(
              bf16x8,
              *(const u16x8*)(Bs + (nq + ni * 16 + ln) * 72 + kt * 32 + q * 8));
#pragma unroll
        for (int mi = 0; mi < 4; ++mi)
#pragma unroll
          for (int ni = 0; ni < 4; ++ni)
            acc[mi][ni] = __builtin_amdgcn_mfma_f32_16x16x32_bf16(
                af[mi], bfr[ni], acc[mi][ni], 0, 0, 0);
      }
    }
    __syncthreads();  // MFMA frag reads done before Ht overwrite

    // hidden = relu(acc + b1) -> Ht bf16
#pragma unroll
    for (int ni = 0; ni < 4; ++ni) {
      float bb = b1[n0 + nq + ni * 16 + ln];
#pragma unroll
      for (int mi = 0; mi < 4; ++mi)
#pragma unroll
        for (int r = 0; r < 4; ++r) {
          float h = fmaxf(acc[mi][ni][r] + bb, 0.f);
          Ht[(mq + mi * 16 + q * 4 + r) * 136 + nq + ni * 16 + ln] = f2bf(h);
        }
    }
    __syncthreads();

    // fc2 partial over this n-slice into registers
    for (int n = 0; n < 128; ++n) {
      float hv = bf2f(Ht[om * 136 + n]);
      const float* w2p = w2 + (size_t)(n0 + n) * Az + oa;
#pragma unroll
      for (int j = 0; j < 8; ++j) oacc[j] += hv * w2p[j];
    }
  }

#pragma unroll
  for (int j = 0; j < 8; ++j)
    out[(r0 + om) * Az + oa + j] = sigmoidf_(oacc[j] + b2[oa + j]);
}

extern "C" void kernel_launch(void* const* d_in, const int* in_sizes, int n_in,
                              void* d_out, int out_size, void* d_ws, size_t ws_size,
                              hipStream_t stream) {
  // Permutation detection from in_sizes (insurance; proven harmless R6/R7)
  int idx_inp = 0, idx_hn = 1, idx_wih = 3, idx_b1 = 5, idx_w2 = 6, idx_b2 = 7;
  int amb1 = -1, amb2 = -1, found = 0;
  for (int i = 0; i < 8 && i < n_in; ++i) {
    switch (in_sizes[i]) {
      case 2097152: idx_inp = i; found |= 1; break;
      case 16384:   idx_hn  = i; found |= 2; break;
      case 32768:   idx_wih = i; found |= 4; break;
      case 512:     idx_b1  = i; found |= 8; break;
      case 8192:    idx_w2  = i; found |= 16; break;
      case 16:      idx_b2  = i; found |= 32; break;
      case 262144:  if (amb1 < 0) amb1 = i; else amb2 = i; break;
    }
  }
  int idx_whh = 2, idx_w1 = 4;  // dict-order fallback
  if (amb1 >= 0 && amb2 >= 0 && found == 63) {
    if (idx_b1 < idx_inp) { idx_w1 = amb1; idx_whh = amb2; }
    else                  { idx_whh = amb1; idx_w1 = amb2; }
  }

  const float* inp = (const float*)d_in[idx_inp];
  const float* hn  = (const float*)d_in[idx_hn];
  const float* whh = (const float*)d_in[idx_whh];
  const float* wih = (const float*)d_in[idx_wih];
  const float* w1  = (const float*)d_in[idx_w1];
  const float* b1  = (const float*)d_in[idx_b1];
  const float* w2  = (const float*)d_in[idx_w2];
  const float* b2  = (const float*)d_in[idx_b2];

  float* out     = (float*)d_out;
  float* out_hn  = out + OFF_HN;
  float* out_rnn = out + OFF_RNN;

  char* ws    = (char*)d_ws;
  int* flags  = (int*)(ws + WS_FLAGS);
  u16* hbuf   = (u16*)(ws + WS_RING);
  u16* whh_bf = (u16*)(ws + WS_WHH);
  u16* wih_bf = (u16*)(ws + WS_WIH);
  u16* w1t_bf = (u16*)(ws + WS_W1T);

  hipMemsetAsync(d_ws, 0, WS_ZERO, stream);
  prep_kernel<<<dim3(2176), dim3(256), 0, stream>>>(whh, wih, w1,
                                                    whh_bf, wih_bf, w1t_bf);
  rnn_scan_kernel<<<dim3(32), dim3(128), 0, stream>>>(
      inp, hn, whh_bf, wih_bf, out_rnn, out_hn, flags, hbuf);
  fc_kernel<<<dim3(256), dim3(256), 0, stream>>>(
      out_rnn, w1t_bf, b1, w2, b2, out);
}